// Round 18
// baseline (696.606 us; speedup 1.0000x reference)
//
#include <hip/hip_runtime.h>
#include <hip/hip_cooperative_groups.h>

namespace cg = cooperative_groups;

#define N_NODES 50000
#define N_EDGES 800000
#define D_FEAT  256
#define N_CLASS 40
#define NSCAN_BLOCKS ((N_NODES + 255) / 256)   // 196
#define NODES_PER_XCD 6250                     // 50000 / 8

typedef __attribute__((ext_vector_type(8))) short short8;
typedef __attribute__((ext_vector_type(4))) float f32x4;

#define SBAR() __builtin_amdgcn_sched_barrier(0)

__device__ __forceinline__ float bf2f(unsigned short u) {
    unsigned int x = ((unsigned int)u) << 16;
    return __builtin_bit_cast(float, x);
}
__device__ __forceinline__ unsigned short f2bf(float f) {
    unsigned int x = __builtin_bit_cast(unsigned int, f);
    x += 0x7fff + ((x >> 16) & 1);   // RTNE
    return (unsigned short)(x >> 16);
}

// ---------------- prep: cvt x -> bf16, weights -> concatenated bf16 ----------------
__global__ void prep_kernel(const float* __restrict__ x,
                            const float* __restrict__ w1l, const float* __restrict__ w1r,
                            const float* __restrict__ w2l, const float* __restrict__ w2r,
                            unsigned short* __restrict__ xb,
                            unsigned short* __restrict__ w1cat, unsigned short* __restrict__ w2cat) {
    const int b = blockIdx.x;
    const int tid = threadIdx.x;
    if (b < 12500) {                      // x convert: 3,200,000 float4s
        const int i = b * 256 + tid;
        float4 v = reinterpret_cast<const float4*>(x)[i];
        ushort4 o;
        o.x = f2bf(v.x); o.y = f2bf(v.y); o.z = f2bf(v.z); o.w = f2bf(v.w);
        reinterpret_cast<ushort4*>(xb)[i] = o;
    } else {                              // weights: 37,888 float4s
        const int i = (b - 12500) * 256 + tid;
        const int N1 = 256 * 128;
        const int N2 = 80 * 64;
        const float* s; unsigned short* dptr;
        if (i < N1) {
            int n = i >> 7, kq = i & 127;
            s = (kq < 64) ? (w1l + n * 256 + kq * 4) : (w1r + n * 256 + (kq - 64) * 4);
            dptr = w1cat + n * 512 + kq * 4;
        } else if (i < N1 + N2) {
            int j = i - N1;
            int n = j >> 6, kq = j & 63;
            s = (n < 40) ? (w2l + n * 256 + kq * 4) : (w2r + (n - 40) * 256 + kq * 4);
            dptr = w2cat + n * 256 + kq * 4;
        } else return;
        float4 v = *reinterpret_cast<const float4*>(s);
        ushort4 o;
        o.x = f2bf(v.x); o.y = f2bf(v.y); o.z = f2bf(v.z); o.w = f2bf(v.w);
        *reinterpret_cast<ushort4*>(dptr) = o;
    }
}

// ---------------- cooperative CSR build: hist -> scan -> offsets -> fill ----------------
// 1024 blocks x 256 threads (4 blocks/CU -> co-resident). XCD q = bid&7 owns node range
// [q*6250,(q+1)*6250); sub = bid>>3 owns edge chunk [sub*6250,(sub+1)*6250).
// escan aliases row_off (phase 3 reads then overwrites same index).
__global__ __launch_bounds__(256)
void csr_coop_kernel(const int* __restrict__ src, const int* __restrict__ dst,
                     int* __restrict__ cursor, int* __restrict__ bsum,
                     int* __restrict__ row_off, int* __restrict__ csr) {
    cg::grid_group grid = cg::this_grid();
    __shared__ int s[256];
    const int bid = blockIdx.x;
    const int tid = threadIdx.x;
    const int q = bid & 7;
    const int sub = bid >> 3;                 // 0..127
    const int lo = q * NODES_PER_XCD, hi = lo + NODES_PER_XCD;
    const int ebase = sub * 6250;             // 128 * 6250 = 800000

    // phase 1: XCD-filtered degree histogram (cursor pre-zeroed by memset)
    for (int e = ebase + tid; e < ebase + 6250; e += 256) {
        const int d = dst[e];
        if (d >= lo && d < hi) atomicAdd(&cursor[d], 1);
    }
    __threadfence();
    grid.sync();

    // phase 2: per-block exclusive scan over cursor -> escan(=row_off) + block sums
    if (bid < NSCAN_BLOCKS) {
        const int i = bid * 256 + tid;
        const int v = (i < N_NODES) ? cursor[i] : 0;
        s[tid] = v;
        __syncthreads();
        #pragma unroll
        for (int off = 1; off < 256; off <<= 1) {
            int u = (tid >= off) ? s[tid - off] : 0;
            __syncthreads();
            s[tid] += u;
            __syncthreads();
        }
        if (i < N_NODES) row_off[i] = s[tid] - v;   // in-block exclusive (escan)
        if (tid == 255) bsum[bid] = s[255];
    }
    __threadfence();
    grid.sync();

    // phase 3: every scan block re-scans bsum in LDS, applies offset -> row_off, cursor
    if (bid < NSCAN_BLOCKS) {
        s[tid] = (tid < NSCAN_BLOCKS) ? bsum[tid] : 0;
        __syncthreads();
        #pragma unroll
        for (int off = 1; off < 256; off <<= 1) {
            int u = (tid >= off) ? s[tid - off] : 0;
            __syncthreads();
            s[tid] += u;
            __syncthreads();
        }
        const int boff = (bid == 0) ? 0 : s[bid - 1];
        const int i = bid * 256 + tid;
        if (i < N_NODES) {
            const int vv = row_off[i] + boff;
            row_off[i] = vv;
            cursor[i] = vv;
        }
        if (bid == 0 && tid == 0) row_off[N_NODES] = s[NSCAN_BLOCKS - 1];
    }
    __threadfence();
    grid.sync();

    // phase 4: XCD-filtered CSR fill
    for (int e = ebase + tid; e < ebase + 6250; e += 256) {
        const int d = dst[e];
        if (d >= lo && d < hi) {
            const int pos = atomicAdd(&cursor[d], 1);
            csr[pos] = src[e];
        }
    }
}

// ---------------- bf16 gather-aggregate + mean, feature-QUARTER XCD split ----------------
// quarter = 64 feats = 128 B = exactly one L2 line per owner XCD (R16: eighth = half-line,
// 2x FETCH). 6.4 MB/XCD working set. ~48.5 us = practical floor for this access pattern.
__global__ __launch_bounds__(256)
void sage_gather_kernel(const unsigned short* __restrict__ feat,
                        const int* __restrict__ row_off,
                        const int* __restrict__ csr,
                        unsigned short* __restrict__ agg) {
    const int bid = blockIdx.x;
    const int quarter = (bid >> 1) & 3;
    const int node = ((bid >> 3) * 2 + (bid & 1)) * 32 + (threadIdx.x >> 3);
    const int c8 = (threadIdx.x & 7) * 8 + quarter * 64;
    if (node >= N_NODES) return;
    const int k0 = row_off[node];
    const int k1 = row_off[node + 1];
    float ax[4], ay[4];
    #pragma unroll
    for (int q = 0; q < 4; ++q) { ax[q] = 0.f; ay[q] = 0.f; }

    int k = k0;
    const int nb = (k1 - k0) >> 3;
    for (int b = 0; b < nb; ++b, k += 8) {
        uint4 buf[8];
        #pragma unroll
        for (int j = 0; j < 8; ++j)
            buf[j] = *reinterpret_cast<const uint4*>(feat + (size_t)csr[k + j] * D_FEAT + c8);
        #pragma unroll
        for (int j = 0; j < 8; ++j) {
            #pragma unroll
            for (int q = 0; q < 4; ++q) {
                const unsigned int d = (&buf[j].x)[q];
                ax[q] += __builtin_bit_cast(float, d << 16);
                ay[q] += __builtin_bit_cast(float, d & 0xffff0000u);
            }
        }
    }
    if (k < k1) {
        const int cnt = k1 - k;
        uint4 tv[7];
        #pragma unroll
        for (int j = 0; j < 7; ++j)
            if (j < cnt)
                tv[j] = *reinterpret_cast<const uint4*>(feat + (size_t)csr[k + j] * D_FEAT + c8);
        #pragma unroll
        for (int j = 0; j < 7; ++j)
            if (j < cnt) {
                #pragma unroll
                for (int q = 0; q < 4; ++q) {
                    const unsigned int d = (&tv[j].x)[q];
                    ax[q] += __builtin_bit_cast(float, d << 16);
                    ay[q] += __builtin_bit_cast(float, d & 0xffff0000u);
                }
            }
    }

    const float sc = 1.0f / fmaxf((float)(k1 - k0), 1.0f);
    short8 o;
    #pragma unroll
    for (int q = 0; q < 4; ++q) {
        o[2 * q]     = (short)f2bf(ax[q] * sc);
        o[2 * q + 1] = (short)f2bf(ay[q] * sc);
    }
    *reinterpret_cast<short8*>(agg + (size_t)node * D_FEAT + c8) = o;
}

// ---------------- GEMM1 (R12 proven shape): h = relu([agg|x] @ w1cat^T + b1) ----------------
__global__ __launch_bounds__(256, 2)
void sage_gemm1_kernel(const unsigned short* __restrict__ agg,
                       const unsigned short* __restrict__ xb,
                       const unsigned short* __restrict__ w1cat,
                       const float* __restrict__ b1l, const float* __restrict__ b1r,
                       unsigned short* __restrict__ h) {
    __shared__ unsigned short Bl[64 * 512];   // 64 KB

    const int t = (blockIdx.x & 7) * 98 + (blockIdx.x >> 3);   // bijective: 784 = 8*98
    const int xblk = t >> 2;
    const int yblk = t & 3;
    const int c0 = yblk * 64;

    const int tid = threadIdx.x;
    const int wid = tid >> 6;
    const int lane = tid & 63;
    const int l15 = lane & 15, l4 = lane >> 4;
    const int r0 = xblk * 256 + wid * 64;

    #pragma unroll
    for (int r = 0; r < 16; ++r) {
        const int idx = r * 256 + tid;
        const int cl = idx >> 6, kc = idx & 63;
        short8 v = *reinterpret_cast<const short8*>(w1cat + (size_t)(c0 + cl) * 512 + kc * 8);
        *reinterpret_cast<short8*>((char*)Bl + cl * 1024 + ((kc * 16) ^ ((cl & 7) << 4))) = v;
    }
    __syncthreads();

    int arow[4];
    #pragma unroll
    for (int mi = 0; mi < 4; ++mi) {
        int r = r0 + mi * 16 + l15;
        arow[mi] = (r < N_NODES) ? r : (N_NODES - 1);
    }

    f32x4 acc[4][4] = {};
    short8 aA[4], aB[4], aC[4], bA[4], bB[4];

#define LA(buf, s)                                                                 \
    {                                                                              \
        const unsigned short* As_ = ((s) < 8) ? agg : xb;                          \
        const int kb_ = ((s) & 7) * 32 + l4 * 8;                                   \
        _Pragma("unroll")                                                          \
        for (int mi = 0; mi < 4; ++mi)                                             \
            buf[mi] = *reinterpret_cast<const short8*>(                            \
                As_ + (size_t)arow[mi] * D_FEAT + kb_);                            \
    }
#define LB(buf, s)                                                                 \
    {                                                                              \
        _Pragma("unroll")                                                          \
        for (int ni = 0; ni < 4; ++ni) {                                           \
            const int cl_ = ni * 16 + l15;                                         \
            buf[ni] = *reinterpret_cast<const short8*>(                            \
                (const char*)Bl + cl_ * 1024 +                                     \
                (((s) * 64 + l4 * 16) ^ ((cl_ & 7) << 4)));                        \
        }                                                                          \
    }
#define MM(ab, bb)                                                                 \
    _Pragma("unroll")                                                              \
    for (int mi = 0; mi < 4; ++mi)                                                 \
        _Pragma("unroll")                                                          \
        for (int ni = 0; ni < 4; ++ni)                                             \
            acc[mi][ni] = __builtin_amdgcn_mfma_f32_16x16x32_bf16(                 \
                ab[mi], bb[ni], acc[mi][ni], 0, 0, 0);

    LA(aA, 0) LA(aB, 1) LB(bA, 0) SBAR();
    LA(aC, 2)  LB(bB, 1)  SBAR(); MM(aA, bA) SBAR();
    LA(aA, 3)  LB(bA, 2)  SBAR(); MM(aB, bB) SBAR();
    LA(aB, 4)  LB(bB, 3)  SBAR(); MM(aC, bA) SBAR();
    LA(aC, 5)  LB(bA, 4)  SBAR(); MM(aA, bB) SBAR();
    LA(aA, 6)  LB(bB, 5)  SBAR(); MM(aB, bA) SBAR();
    LA(aB, 7)  LB(bA, 6)  SBAR(); MM(aC, bB) SBAR();
    LA(aC, 8)  LB(bB, 7)  SBAR(); MM(aA, bA) SBAR();
    LA(aA, 9)  LB(bA, 8)  SBAR(); MM(aB, bB) SBAR();
    LA(aB, 10) LB(bB, 9)  SBAR(); MM(aC, bA) SBAR();
    LA(aC, 11) LB(bA, 10) SBAR(); MM(aA, bB) SBAR();
    LA(aA, 12) LB(bB, 11) SBAR(); MM(aB, bA) SBAR();
    LA(aB, 13) LB(bA, 12) SBAR(); MM(aC, bB) SBAR();
    LA(aC, 14) LB(bB, 13) SBAR(); MM(aA, bA) SBAR();
    LA(aA, 15) LB(bA, 14) SBAR(); MM(aB, bB) SBAR();
    LB(bB, 15) SBAR();            MM(aC, bA) SBAR();
    MM(aA, bB)
#undef LA
#undef LB
#undef MM

    #pragma unroll
    for (int ni = 0; ni < 4; ++ni) {
        const int c = c0 + ni * 16 + l15;
        const float bias = b1l[c] + b1r[c];
        #pragma unroll
        for (int mi = 0; mi < 4; ++mi) {
            #pragma unroll
            for (int i = 0; i < 4; ++i) {
                const int r = r0 + mi * 16 + l4 * 4 + i;
                if (r >= N_NODES) continue;
                h[(size_t)r * D_FEAT + c] = f2bf(fmaxf(acc[mi][ni][i] + bias, 0.f));
            }
        }
    }
}

// ---------------- GEMM2: u = h@W2l^T, v = h@W2r^T + b2  (bf16 out), weights-stationary ----------------
__global__ __launch_bounds__(256, 2)
void sage_gemm2_kernel(const unsigned short* __restrict__ hb,
                       const unsigned short* __restrict__ w2cat,
                       const float* __restrict__ b2l, const float* __restrict__ b2r,
                       unsigned short* __restrict__ u, unsigned short* __restrict__ v) {
    __shared__ unsigned short Bl[80 * 256];   // 40 KB

    const int tid = threadIdx.x;
    const int wid = tid >> 6;
    const int lane = tid & 63;
    const int l15 = lane & 15, l4 = lane >> 4;
    const int r0 = blockIdx.x * 256 + wid * 64;

    #pragma unroll
    for (int r = 0; r < 10; ++r) {
        const int idx = r * 256 + tid;
        const int cl = idx >> 5, kc = idx & 31;
        short8 vch = *reinterpret_cast<const short8*>(w2cat + (size_t)cl * 256 + kc * 8);
        *reinterpret_cast<short8*>((char*)Bl + cl * 512 + ((kc * 16) ^ ((cl & 7) << 4))) = vch;
    }
    __syncthreads();

    int arow[4];
    #pragma unroll
    for (int mi = 0; mi < 4; ++mi) {
        int r = r0 + mi * 16 + l15;
        arow[mi] = (r < N_NODES) ? r : (N_NODES - 1);
    }

    f32x4 acc[4][5] = {};
    short8 aA[4], aB[4], aC[4], bA[5], bB[5];

#define LA2(buf, s)                                                                \
    {                                                                              \
        const int kb_ = (s) * 32 + l4 * 8;                                         \
        _Pragma("unroll")                                                          \
        for (int mi = 0; mi < 4; ++mi)                                             \
            buf[mi] = *reinterpret_cast<const short8*>(                            \
                hb + (size_t)arow[mi] * D_FEAT + kb_);                             \
    }
#define LB2(buf, s)                                                                \
    {                                                                              \
        _Pragma("unroll")                                                          \
        for (int ni = 0; ni < 5; ++ni) {                                           \
            const int cl_ = ni * 16 + l15;                                         \
            buf[ni] = *reinterpret_cast<const short8*>(                            \
                (const char*)Bl + cl_ * 512 +                                      \
                (((s) * 64 + l4 * 16) ^ ((cl_ & 7) << 4)));                        \
        }                                                                          \
    }
#define MM2(ab, bb)                                                                \
    _Pragma("unroll")                                                              \
    for (int mi = 0; mi < 4; ++mi)                                                 \
        _Pragma("unroll")                                                          \
        for (int ni = 0; ni < 5; ++ni)                                             \
            acc[mi][ni] = __builtin_amdgcn_mfma_f32_16x16x32_bf16(                 \
                ab[mi], bb[ni], acc[mi][ni], 0, 0, 0);

    LA2(aA, 0) LA2(aB, 1) LB2(bA, 0) SBAR();
    LA2(aC, 2) LB2(bB, 1) SBAR(); MM2(aA, bA) SBAR();
    LA2(aA, 3) LB2(bA, 2) SBAR(); MM2(aB, bB) SBAR();
    LA2(aB, 4) LB2(bB, 3) SBAR(); MM2(aC, bA) SBAR();
    LA2(aC, 5) LB2(bA, 4) SBAR(); MM2(aA, bB) SBAR();
    LA2(aA, 6) LB2(bB, 5) SBAR(); MM2(aB, bA) SBAR();
    LA2(aB, 7) LB2(bA, 6) SBAR(); MM2(aC, bB) SBAR();
    LB2(bB, 7) SBAR();            MM2(aA, bA) SBAR();
    MM2(aB, bB)
#undef LA2
#undef LB2
#undef MM2

    #pragma unroll
    for (int ni = 0; ni < 5; ++ni) {
        const int c = ni * 16 + l15;             // 0..79
        const bool is_u = (c < N_CLASS);
        const float bias = is_u ? 0.f : (b2l[c - N_CLASS] + b2r[c - N_CLASS]);
        #pragma unroll
        for (int mi = 0; mi < 4; ++mi) {
            #pragma unroll
            for (int i = 0; i < 4; ++i) {
                const int r = r0 + mi * 16 + l4 * 4 + i;
                if (r >= N_NODES) continue;
                const unsigned short val = f2bf(acc[mi][ni][i] + bias);
                if (is_u) u[(size_t)r * N_CLASS + c] = val;
                else      v[(size_t)r * N_CLASS + (c - N_CLASS)] = val;
            }
        }
    }
}

// ---------------- gather2: out = agg(u) + v  (40-dim, bf16) ----------------
__global__ __launch_bounds__(256)
void sage_gather2_kernel(const unsigned short* __restrict__ u, const unsigned short* __restrict__ v,
                         const int* __restrict__ row_off, const int* __restrict__ csr,
                         float* __restrict__ out) {
    const int tid = threadIdx.x;
    const int lane = tid & 63;
    const int slot = lane / 20;          // 0..2 valid, 3 idle
    const int li = lane - slot * 20;
    if (slot >= 3) return;
    const int node = blockIdx.x * 12 + (tid >> 6) * 3 + slot;
    if (node >= N_NODES) return;
    const int c2 = li * 2;
    const int k0 = row_off[node];
    const int k1 = row_off[node + 1];
    float a0 = 0.f, a1 = 0.f;

    int k = k0;
    const int nb = (k1 - k0) >> 3;
    for (int b = 0; b < nb; ++b, k += 8) {
        unsigned int buf[8];
        #pragma unroll
        for (int j = 0; j < 8; ++j)
            buf[j] = *reinterpret_cast<const unsigned int*>(u + (size_t)csr[k + j] * N_CLASS + c2);
        #pragma unroll
        for (int j = 0; j < 8; ++j) {
            a0 += bf2f((unsigned short)(buf[j] & 0xffffu));
            a1 += bf2f((unsigned short)(buf[j] >> 16));
        }
    }
    if (k < k1) {
        const int cnt = k1 - k;
        unsigned int tv[7];
        #pragma unroll
        for (int j = 0; j < 7; ++j)
            if (j < cnt)
                tv[j] = *reinterpret_cast<const unsigned int*>(u + (size_t)csr[k + j] * N_CLASS + c2);
        #pragma unroll
        for (int j = 0; j < 7; ++j)
            if (j < cnt) {
                a0 += bf2f((unsigned short)(tv[j] & 0xffffu));
                a1 += bf2f((unsigned short)(tv[j] >> 16));
            }
    }

    const float sc = 1.0f / fmaxf((float)(k1 - k0), 1.0f);
    const unsigned int vv = *reinterpret_cast<const unsigned int*>(v + (size_t)node * N_CLASS + c2);
    float2 o;
    o.x = a0 * sc + bf2f((unsigned short)(vv & 0xffffu));
    o.y = a1 * sc + bf2f((unsigned short)(vv >> 16));
    *reinterpret_cast<float2*>(out + (size_t)node * N_CLASS + c2) = o;
}

extern "C" void kernel_launch(void* const* d_in, const int* in_sizes, int n_in,
                              void* d_out, int out_size, void* d_ws, size_t ws_size,
                              hipStream_t stream) {
    const float* x    = (const float*)d_in[0];
    const int*   ei   = (const int*)d_in[1];
    const float* w1l  = (const float*)d_in[2];
    const float* b1l  = (const float*)d_in[3];
    const float* w1r  = (const float*)d_in[4];
    const float* b1r  = (const float*)d_in[5];
    const float* w2l  = (const float*)d_in[6];
    const float* b2l  = (const float*)d_in[7];
    const float* w2r  = (const float*)d_in[8];
    const float* b2r  = (const float*)d_in[9];
    float* out = (float*)d_out;

    const int* src = ei;
    const int* dst = ei + N_EDGES;

    // workspace layout (bytes)
    const size_t FEAT_BYTES  = (size_t)N_NODES * D_FEAT * 2;           // 25.6 MB
    const size_t ROW_OFF_OFF = 0;
    const size_t CURSOR_OFF  = 204800;
    const size_t BSUM_OFF    = 409600;
    const size_t CSR_OFF     = 410624;
    const size_t XB_OFF      = CSR_OFF + (size_t)N_EDGES * 4 + 1024;   // 3,611,648
    const size_t AGG_OFF     = XB_OFF + FEAT_BYTES;
    const size_t H_OFF       = AGG_OFF + FEAT_BYTES;
    const size_t W1C_OFF     = H_OFF + FEAT_BYTES;
    const size_t W2C_OFF     = W1C_OFF + 262144;
    const size_t U_OFF       = W2C_OFF + 40960;
    const size_t V_OFF       = U_OFF + (size_t)N_NODES * N_CLASS * 2;  // bf16 u

    int* row_off = (int*)((char*)d_ws + ROW_OFF_OFF);
    int* cursor  = (int*)((char*)d_ws + CURSOR_OFF);
    int* bsum    = (int*)((char*)d_ws + BSUM_OFF);
    int* csr     = (int*)((char*)d_ws + CSR_OFF);
    unsigned short* xb    = (unsigned short*)((char*)d_ws + XB_OFF);
    unsigned short* aggb  = (unsigned short*)((char*)d_ws + AGG_OFF);
    unsigned short* hb    = (unsigned short*)((char*)d_ws + H_OFF);
    unsigned short* w1cat = (unsigned short*)((char*)d_ws + W1C_OFF);
    unsigned short* w2cat = (unsigned short*)((char*)d_ws + W2C_OFF);
    unsigned short* u = (unsigned short*)((char*)d_ws + U_OFF);
    unsigned short* v = (unsigned short*)((char*)d_ws + V_OFF);

    // ---- prep (cvt x, cvt weights) + zero cursor ----
    hipMemsetAsync(cursor, 0, (size_t)N_NODES * 4, stream);
    prep_kernel<<<12648, 256, 0, stream>>>(x, w1l, w1r, w2l, w2r, xb, w1cat, w2cat);

    // ---- CSR build: one cooperative dispatch (hist -> scan -> offsets -> fill) ----
    {
        void* args[] = {(void*)&src, (void*)&dst, (void*)&cursor,
                        (void*)&bsum, (void*)&row_off, (void*)&csr};
        hipLaunchCooperativeKernel((void*)csr_coop_kernel, dim3(1024), dim3(256),
                                   args, 0, stream);
    }

    // ---- layer 1 ----
    sage_gather_kernel<<<6256, 256, 0, stream>>>(xb, row_off, csr, aggb);
    sage_gemm1_kernel<<<784, 256, 0, stream>>>(aggb, xb, w1cat, b1l, b1r, hb);

    // ---- layer 2 (transform-then-aggregate) ----
    sage_gemm2_kernel<<<196, 256, 0, stream>>>(hb, w2cat, b2l, b2r, u, v);
    sage_gather2_kernel<<<(N_NODES + 11) / 12, 256, 0, stream>>>(u, v, row_off, csr, out);

    (void)in_sizes; (void)n_in; (void)out_size; (void)ws_size;
}

// Round 19
// 209.840 us; speedup vs baseline: 3.3197x; 3.3197x over previous
//
#include <hip/hip_runtime.h>

#define N_NODES 50000
#define N_EDGES 800000
#define D_FEAT  256
#define N_CLASS 40
#define NSCAN_BLOCKS ((N_NODES + 255) / 256)   // 196
#define NODES_PER_XCD 6250                     // 50000 / 8
#define HIST_BLOCKS 3128                       // 8 * 391

typedef __attribute__((ext_vector_type(8))) short short8;
typedef __attribute__((ext_vector_type(4))) float f32x4;

#define SBAR() __builtin_amdgcn_sched_barrier(0)

__device__ __forceinline__ float bf2f(unsigned short u) {
    unsigned int x = ((unsigned int)u) << 16;
    return __builtin_bit_cast(float, x);
}
__device__ __forceinline__ unsigned short f2bf(float f) {
    unsigned int x = __builtin_bit_cast(unsigned int, f);
    x += 0x7fff + ((x >> 16) & 1);   // RTNE
    return (unsigned short)(x >> 16);
}

// ---- fused prep: HIST FIRST (blocks 0..3127, overlaps with converts), then cvt x, weights ----
// Hist is atomic/latency-bound, converts are BW-bound -> concurrent, prep ~= max not sum (R17 lesson).
__global__ void prep_kernel(const float* __restrict__ x,
                            const float* __restrict__ w1l, const float* __restrict__ w1r,
                            const float* __restrict__ w2l, const float* __restrict__ w2r,
                            const int* __restrict__ dst,
                            unsigned short* __restrict__ xb,
                            unsigned short* __restrict__ w1cat, unsigned short* __restrict__ w2cat,
                            int* __restrict__ cursor) {
    const int b = blockIdx.x;
    const int tid = threadIdx.x;
    if (b < HIST_BLOCKS) {                // XCD-range-filtered degree histogram
        const int q = b & 7;
        const int sub = b >> 3;           // 0..390
        const int lo = q * NODES_PER_XCD, hi = lo + NODES_PER_XCD;
        const int base = sub * 2048 + tid;
        #pragma unroll
        for (int i = 0; i < 8; ++i) {
            const int e = base + i * 256;
            if (e < N_EDGES) {
                const int d = dst[e];
                if (d >= lo && d < hi) atomicAdd(&cursor[d], 1);
            }
        }
    } else if (b < HIST_BLOCKS + 12500) { // x convert: 3,200,000 float4s
        const int i = (b - HIST_BLOCKS) * 256 + tid;
        float4 v = reinterpret_cast<const float4*>(x)[i];
        ushort4 o;
        o.x = f2bf(v.x); o.y = f2bf(v.y); o.z = f2bf(v.z); o.w = f2bf(v.w);
        reinterpret_cast<ushort4*>(xb)[i] = o;
    } else {                              // weights: 37,888 float4s
        const int i = (b - HIST_BLOCKS - 12500) * 256 + tid;
        const int N1 = 256 * 128;
        const int N2 = 80 * 64;
        const float* s; unsigned short* dptr;
        if (i < N1) {
            int n = i >> 7, kq = i & 127;
            s = (kq < 64) ? (w1l + n * 256 + kq * 4) : (w1r + n * 256 + (kq - 64) * 4);
            dptr = w1cat + n * 512 + kq * 4;
        } else if (i < N1 + N2) {
            int j = i - N1;
            int n = j >> 6, kq = j & 63;
            s = (n < 40) ? (w2l + n * 256 + kq * 4) : (w2r + (n - 40) * 256 + kq * 4);
            dptr = w2cat + n * 256 + kq * 4;
        } else return;
        float4 v = *reinterpret_cast<const float4*>(s);
        ushort4 o;
        o.x = f2bf(v.x); o.y = f2bf(v.y); o.z = f2bf(v.z); o.w = f2bf(v.w);
        *reinterpret_cast<ushort4*>(dptr) = o;
    }
}

// ---------------- scan phase 1: per-block exclusive scan + raw block sums ----------------
__global__ __launch_bounds__(256)
void scan_local_kernel(const int* __restrict__ deg, int* __restrict__ escan, int* __restrict__ bsum) {
    __shared__ int s[256];
    const int t = threadIdx.x;
    const int i = blockIdx.x * 256 + t;
    const int v = (i < N_NODES) ? deg[i] : 0;
    s[t] = v;
    __syncthreads();
    #pragma unroll
    for (int off = 1; off < 256; off <<= 1) {
        int u = (t >= off) ? s[t - off] : 0;
        __syncthreads();
        s[t] += u;
        __syncthreads();
    }
    if (i < N_NODES) escan[i] = s[t] - v;
    if (t == 255) bsum[blockIdx.x] = s[255];
}

// ---------------- scan phase 2 (fused): every block scans raw bsums, applies offset ----------
__global__ __launch_bounds__(256)
void scan_add_kernel(const int* __restrict__ escan_in, const int* __restrict__ bsum,
                     int* __restrict__ row_off, int* __restrict__ cursor) {
    __shared__ int s[256];
    const int t = threadIdx.x;
    s[t] = (t < NSCAN_BLOCKS) ? bsum[t] : 0;
    __syncthreads();
    #pragma unroll
    for (int off = 1; off < 256; off <<= 1) {
        int u = (t >= off) ? s[t - off] : 0;
        __syncthreads();
        s[t] += u;
        __syncthreads();
    }
    const int boff = (blockIdx.x == 0) ? 0 : s[blockIdx.x - 1];
    const int i = blockIdx.x * 256 + t;
    if (i < N_NODES) {
        const int v = escan_in[i] + boff;
        row_off[i] = v;
        cursor[i] = v;
    }
    if (blockIdx.x == 0 && t == 0) row_off[N_NODES] = s[NSCAN_BLOCKS - 1];
}

// ---------------- CSR fill, XCD-range filtered ----------------
__global__ __launch_bounds__(256)
void sage_fill_kernel(const int* __restrict__ src, const int* __restrict__ dst,
                      int* __restrict__ cursor, int* __restrict__ csr) {
    const int q = blockIdx.x & 7;
    const int sub = blockIdx.x >> 3;
    const int lo = q * NODES_PER_XCD, hi = lo + NODES_PER_XCD;
    const int base = sub * 2048 + threadIdx.x;
    #pragma unroll
    for (int i = 0; i < 8; ++i) {
        const int e = base + i * 256;
        if (e < N_EDGES) {
            const int d = dst[e];
            if (d >= lo && d < hi) {
                const int pos = atomicAdd(&cursor[d], 1);
                csr[pos] = src[e];
            }
        }
    }
}

// ---------------- bf16 gather-aggregate + mean, feature-QUARTER XCD split ----------------
// quarter = 64 feats = 128 B = one L2 line per owner XCD (R16: eighth = half-line, 2x FETCH).
__global__ __launch_bounds__(256)
void sage_gather_kernel(const unsigned short* __restrict__ feat,
                        const int* __restrict__ row_off,
                        const int* __restrict__ csr,
                        unsigned short* __restrict__ agg) {
    const int bid = blockIdx.x;
    const int quarter = (bid >> 1) & 3;
    const int node = ((bid >> 3) * 2 + (bid & 1)) * 32 + (threadIdx.x >> 3);
    const int c8 = (threadIdx.x & 7) * 8 + quarter * 64;
    if (node >= N_NODES) return;
    const int k0 = row_off[node];
    const int k1 = row_off[node + 1];
    float ax[4], ay[4];
    #pragma unroll
    for (int q = 0; q < 4; ++q) { ax[q] = 0.f; ay[q] = 0.f; }

    int k = k0;
    const int nb = (k1 - k0) >> 3;
    for (int b = 0; b < nb; ++b, k += 8) {
        uint4 buf[8];
        #pragma unroll
        for (int j = 0; j < 8; ++j)
            buf[j] = *reinterpret_cast<const uint4*>(feat + (size_t)csr[k + j] * D_FEAT + c8);
        #pragma unroll
        for (int j = 0; j < 8; ++j) {
            #pragma unroll
            for (int q = 0; q < 4; ++q) {
                const unsigned int d = (&buf[j].x)[q];
                ax[q] += __builtin_bit_cast(float, d << 16);
                ay[q] += __builtin_bit_cast(float, d & 0xffff0000u);
            }
        }
    }
    if (k < k1) {
        const int cnt = k1 - k;
        uint4 tv[7];
        #pragma unroll
        for (int j = 0; j < 7; ++j)
            if (j < cnt)
                tv[j] = *reinterpret_cast<const uint4*>(feat + (size_t)csr[k + j] * D_FEAT + c8);
        #pragma unroll
        for (int j = 0; j < 7; ++j)
            if (j < cnt) {
                #pragma unroll
                for (int q = 0; q < 4; ++q) {
                    const unsigned int d = (&tv[j].x)[q];
                    ax[q] += __builtin_bit_cast(float, d << 16);
                    ay[q] += __builtin_bit_cast(float, d & 0xffff0000u);
                }
            }
    }

    const float sc = 1.0f / fmaxf((float)(k1 - k0), 1.0f);
    short8 o;
    #pragma unroll
    for (int q = 0; q < 4; ++q) {
        o[2 * q]     = (short)f2bf(ax[q] * sc);
        o[2 * q + 1] = (short)f2bf(ay[q] * sc);
    }
    *reinterpret_cast<short8*>(agg + (size_t)node * D_FEAT + c8) = o;
}

// ---------------- GEMM1 (R12 proven shape): h = relu([agg|x] @ w1cat^T + b1) ----------------
__global__ __launch_bounds__(256, 2)
void sage_gemm1_kernel(const unsigned short* __restrict__ agg,
                       const unsigned short* __restrict__ xb,
                       const unsigned short* __restrict__ w1cat,
                       const float* __restrict__ b1l, const float* __restrict__ b1r,
                       unsigned short* __restrict__ h) {
    __shared__ unsigned short Bl[64 * 512];   // 64 KB

    const int t = (blockIdx.x & 7) * 98 + (blockIdx.x >> 3);   // bijective: 784 = 8*98
    const int xblk = t >> 2;
    const int yblk = t & 3;
    const int c0 = yblk * 64;

    const int tid = threadIdx.x;
    const int wid = tid >> 6;
    const int lane = tid & 63;
    const int l15 = lane & 15, l4 = lane >> 4;
    const int r0 = xblk * 256 + wid * 64;

    #pragma unroll
    for (int r = 0; r < 16; ++r) {
        const int idx = r * 256 + tid;
        const int cl = idx >> 6, kc = idx & 63;
        short8 v = *reinterpret_cast<const short8*>(w1cat + (size_t)(c0 + cl) * 512 + kc * 8);
        *reinterpret_cast<short8*>((char*)Bl + cl * 1024 + ((kc * 16) ^ ((cl & 7) << 4))) = v;
    }
    __syncthreads();

    int arow[4];
    #pragma unroll
    for (int mi = 0; mi < 4; ++mi) {
        int r = r0 + mi * 16 + l15;
        arow[mi] = (r < N_NODES) ? r : (N_NODES - 1);
    }

    f32x4 acc[4][4] = {};
    short8 aA[4], aB[4], aC[4], bA[4], bB[4];

#define LA(buf, s)                                                                 \
    {                                                                              \
        const unsigned short* As_ = ((s) < 8) ? agg : xb;                          \
        const int kb_ = ((s) & 7) * 32 + l4 * 8;                                   \
        _Pragma("unroll")                                                          \
        for (int mi = 0; mi < 4; ++mi)                                             \
            buf[mi] = *reinterpret_cast<const short8*>(                            \
                As_ + (size_t)arow[mi] * D_FEAT + kb_);                            \
    }
#define LB(buf, s)                                                                 \
    {                                                                              \
        _Pragma("unroll")                                                          \
        for (int ni = 0; ni < 4; ++ni) {                                           \
            const int cl_ = ni * 16 + l15;                                         \
            buf[ni] = *reinterpret_cast<const short8*>(                            \
                (const char*)Bl + cl_ * 1024 +                                     \
                (((s) * 64 + l4 * 16) ^ ((cl_ & 7) << 4)));                        \
        }                                                                          \
    }
#define MM(ab, bb)                                                                 \
    _Pragma("unroll")                                                              \
    for (int mi = 0; mi < 4; ++mi)                                                 \
        _Pragma("unroll")                                                          \
        for (int ni = 0; ni < 4; ++ni)                                             \
            acc[mi][ni] = __builtin_amdgcn_mfma_f32_16x16x32_bf16(                 \
                ab[mi], bb[ni], acc[mi][ni], 0, 0, 0);

    LA(aA, 0) LA(aB, 1) LB(bA, 0) SBAR();
    LA(aC, 2)  LB(bB, 1)  SBAR(); MM(aA, bA) SBAR();
    LA(aA, 3)  LB(bA, 2)  SBAR(); MM(aB, bB) SBAR();
    LA(aB, 4)  LB(bB, 3)  SBAR(); MM(aC, bA) SBAR();
    LA(aC, 5)  LB(bA, 4)  SBAR(); MM(aA, bB) SBAR();
    LA(aA, 6)  LB(bB, 5)  SBAR(); MM(aB, bA) SBAR();
    LA(aB, 7)  LB(bA, 6)  SBAR(); MM(aC, bB) SBAR();
    LA(aC, 8)  LB(bB, 7)  SBAR(); MM(aA, bA) SBAR();
    LA(aA, 9)  LB(bA, 8)  SBAR(); MM(aB, bB) SBAR();
    LA(aB, 10) LB(bB, 9)  SBAR(); MM(aC, bA) SBAR();
    LA(aC, 11) LB(bA, 10) SBAR(); MM(aA, bB) SBAR();
    LA(aA, 12) LB(bB, 11) SBAR(); MM(aB, bA) SBAR();
    LA(aB, 13) LB(bA, 12) SBAR(); MM(aC, bB) SBAR();
    LA(aC, 14) LB(bB, 13) SBAR(); MM(aA, bA) SBAR();
    LA(aA, 15) LB(bA, 14) SBAR(); MM(aB, bB) SBAR();
    LB(bB, 15) SBAR();            MM(aC, bA) SBAR();
    MM(aA, bB)
#undef LA
#undef LB
#undef MM

    #pragma unroll
    for (int ni = 0; ni < 4; ++ni) {
        const int c = c0 + ni * 16 + l15;
        const float bias = b1l[c] + b1r[c];
        #pragma unroll
        for (int mi = 0; mi < 4; ++mi) {
            #pragma unroll
            for (int i = 0; i < 4; ++i) {
                const int r = r0 + mi * 16 + l4 * 4 + i;
                if (r >= N_NODES) continue;
                h[(size_t)r * D_FEAT + c] = f2bf(fmaxf(acc[mi][ni][i] + bias, 0.f));
            }
        }
    }
}

// ---------------- GEMM2: u = h@W2l^T, v = h@W2r^T + b2  (bf16 out), weights-stationary ----------------
__global__ __launch_bounds__(256, 2)
void sage_gemm2_kernel(const unsigned short* __restrict__ hb,
                       const unsigned short* __restrict__ w2cat,
                       const float* __restrict__ b2l, const float* __restrict__ b2r,
                       unsigned short* __restrict__ u, unsigned short* __restrict__ v) {
    __shared__ unsigned short Bl[80 * 256];   // 40 KB

    const int tid = threadIdx.x;
    const int wid = tid >> 6;
    const int lane = tid & 63;
    const int l15 = lane & 15, l4 = lane >> 4;
    const int r0 = blockIdx.x * 256 + wid * 64;

    #pragma unroll
    for (int r = 0; r < 10; ++r) {
        const int idx = r * 256 + tid;
        const int cl = idx >> 5, kc = idx & 31;
        short8 vch = *reinterpret_cast<const short8*>(w2cat + (size_t)cl * 256 + kc * 8);
        *reinterpret_cast<short8*>((char*)Bl + cl * 512 + ((kc * 16) ^ ((cl & 7) << 4))) = vch;
    }
    __syncthreads();

    int arow[4];
    #pragma unroll
    for (int mi = 0; mi < 4; ++mi) {
        int r = r0 + mi * 16 + l15;
        arow[mi] = (r < N_NODES) ? r : (N_NODES - 1);
    }

    f32x4 acc[4][5] = {};
    short8 aA[4], aB[4], aC[4], bA[5], bB[5];

#define LA2(buf, s)                                                                \
    {                                                                              \
        const int kb_ = (s) * 32 + l4 * 8;                                         \
        _Pragma("unroll")                                                          \
        for (int mi = 0; mi < 4; ++mi)                                             \
            buf[mi] = *reinterpret_cast<const short8*>(                            \
                hb + (size_t)arow[mi] * D_FEAT + kb_);                             \
    }
#define LB2(buf, s)                                                                \
    {                                                                              \
        _Pragma("unroll")                                                          \
        for (int ni = 0; ni < 5; ++ni) {                                           \
            const int cl_ = ni * 16 + l15;                                         \
            buf[ni] = *reinterpret_cast<const short8*>(                            \
                (const char*)Bl + cl_ * 512 +                                      \
                (((s) * 64 + l4 * 16) ^ ((cl_ & 7) << 4)));                        \
        }                                                                          \
    }
#define MM2(ab, bb)                                                                \
    _Pragma("unroll")                                                              \
    for (int mi = 0; mi < 4; ++mi)                                                 \
        _Pragma("unroll")                                                          \
        for (int ni = 0; ni < 5; ++ni)                                             \
            acc[mi][ni] = __builtin_amdgcn_mfma_f32_16x16x32_bf16(                 \
                ab[mi], bb[ni], acc[mi][ni], 0, 0, 0);

    LA2(aA, 0) LA2(aB, 1) LB2(bA, 0) SBAR();
    LA2(aC, 2) LB2(bB, 1) SBAR(); MM2(aA, bA) SBAR();
    LA2(aA, 3) LB2(bA, 2) SBAR(); MM2(aB, bB) SBAR();
    LA2(aB, 4) LB2(bB, 3) SBAR(); MM2(aC, bA) SBAR();
    LA2(aC, 5) LB2(bA, 4) SBAR(); MM2(aA, bB) SBAR();
    LA2(aA, 6) LB2(bB, 5) SBAR(); MM2(aB, bA) SBAR();
    LA2(aB, 7) LB2(bA, 6) SBAR(); MM2(aC, bB) SBAR();
    LB2(bB, 7) SBAR();            MM2(aA, bA) SBAR();
    MM2(aB, bB)
#undef LA2
#undef LB2
#undef MM2

    #pragma unroll
    for (int ni = 0; ni < 5; ++ni) {
        const int c = ni * 16 + l15;             // 0..79
        const bool is_u = (c < N_CLASS);
        const float bias = is_u ? 0.f : (b2l[c - N_CLASS] + b2r[c - N_CLASS]);
        #pragma unroll
        for (int mi = 0; mi < 4; ++mi) {
            #pragma unroll
            for (int i = 0; i < 4; ++i) {
                const int r = r0 + mi * 16 + l4 * 4 + i;
                if (r >= N_NODES) continue;
                const unsigned short val = f2bf(acc[mi][ni][i] + bias);
                if (is_u) u[(size_t)r * N_CLASS + c] = val;
                else      v[(size_t)r * N_CLASS + (c - N_CLASS)] = val;
            }
        }
    }
}

// ---------------- gather2: out = agg(u) + v  (40-dim, bf16) ----------------
__global__ __launch_bounds__(256)
void sage_gather2_kernel(const unsigned short* __restrict__ u, const unsigned short* __restrict__ v,
                         const int* __restrict__ row_off, const int* __restrict__ csr,
                         float* __restrict__ out) {
    const int tid = threadIdx.x;
    const int lane = tid & 63;
    const int slot = lane / 20;          // 0..2 valid, 3 idle
    const int li = lane - slot * 20;
    if (slot >= 3) return;
    const int node = blockIdx.x * 12 + (tid >> 6) * 3 + slot;
    if (node >= N_NODES) return;
    const int c2 = li * 2;
    const int k0 = row_off[node];
    const int k1 = row_off[node + 1];
    float a0 = 0.f, a1 = 0.f;

    int k = k0;
    const int nb = (k1 - k0) >> 3;
    for (int b = 0; b < nb; ++b, k += 8) {
        unsigned int buf[8];
        #pragma unroll
        for (int j = 0; j < 8; ++j)
            buf[j] = *reinterpret_cast<const unsigned int*>(u + (size_t)csr[k + j] * N_CLASS + c2);
        #pragma unroll
        for (int j = 0; j < 8; ++j) {
            a0 += bf2f((unsigned short)(buf[j] & 0xffffu));
            a1 += bf2f((unsigned short)(buf[j] >> 16));
        }
    }
    if (k < k1) {
        const int cnt = k1 - k;
        unsigned int tv[7];
        #pragma unroll
        for (int j = 0; j < 7; ++j)
            if (j < cnt)
                tv[j] = *reinterpret_cast<const unsigned int*>(u + (size_t)csr[k + j] * N_CLASS + c2);
        #pragma unroll
        for (int j = 0; j < 7; ++j)
            if (j < cnt) {
                a0 += bf2f((unsigned short)(tv[j] & 0xffffu));
                a1 += bf2f((unsigned short)(tv[j] >> 16));
            }
    }

    const float sc = 1.0f / fmaxf((float)(k1 - k0), 1.0f);
    const unsigned int vv = *reinterpret_cast<const unsigned int*>(v + (size_t)node * N_CLASS + c2);
    float2 o;
    o.x = a0 * sc + bf2f((unsigned short)(vv & 0xffffu));
    o.y = a1 * sc + bf2f((unsigned short)(vv >> 16));
    *reinterpret_cast<float2*>(out + (size_t)node * N_CLASS + c2) = o;
}

extern "C" void kernel_launch(void* const* d_in, const int* in_sizes, int n_in,
                              void* d_out, int out_size, void* d_ws, size_t ws_size,
                              hipStream_t stream) {
    const float* x    = (const float*)d_in[0];
    const int*   ei   = (const int*)d_in[1];
    const float* w1l  = (const float*)d_in[2];
    const float* b1l  = (const float*)d_in[3];
    const float* w1r  = (const float*)d_in[4];
    const float* b1r  = (const float*)d_in[5];
    const float* w2l  = (const float*)d_in[6];
    const float* b2l  = (const float*)d_in[7];
    const float* w2r  = (const float*)d_in[8];
    const float* b2r  = (const float*)d_in[9];
    float* out = (float*)d_out;

    const int* src = ei;
    const int* dst = ei + N_EDGES;

    // workspace layout (bytes)
    const size_t FEAT_BYTES  = (size_t)N_NODES * D_FEAT * 2;           // 25.6 MB
    const size_t ROW_OFF_OFF = 0;
    const size_t CURSOR_OFF  = 204800;
    const size_t BSUM_OFF    = 409600;
    const size_t CSR_OFF     = 410624;
    const size_t XB_OFF      = CSR_OFF + (size_t)N_EDGES * 4 + 1024;   // 3,611,648
    const size_t AGG_OFF     = XB_OFF + FEAT_BYTES;
    const size_t H_OFF       = AGG_OFF + FEAT_BYTES;
    const size_t W1C_OFF     = H_OFF + FEAT_BYTES;
    const size_t W2C_OFF     = W1C_OFF + 262144;
    const size_t U_OFF       = W2C_OFF + 40960;
    const size_t V_OFF       = U_OFF + (size_t)N_NODES * N_CLASS * 2;  // bf16 u

    int* row_off = (int*)((char*)d_ws + ROW_OFF_OFF);
    int* cursor  = (int*)((char*)d_ws + CURSOR_OFF);
    int* bsum    = (int*)((char*)d_ws + BSUM_OFF);
    int* csr     = (int*)((char*)d_ws + CSR_OFF);
    unsigned short* xb    = (unsigned short*)((char*)d_ws + XB_OFF);
    unsigned short* aggb  = (unsigned short*)((char*)d_ws + AGG_OFF);
    unsigned short* hb    = (unsigned short*)((char*)d_ws + H_OFF);
    unsigned short* w1cat = (unsigned short*)((char*)d_ws + W1C_OFF);
    unsigned short* w2cat = (unsigned short*)((char*)d_ws + W2C_OFF);
    unsigned short* u = (unsigned short*)((char*)d_ws + U_OFF);
    unsigned short* v = (unsigned short*)((char*)d_ws + V_OFF);

    // ---- fused prep (hist FIRST, then cvt x, cvt weights) ----
    hipMemsetAsync(cursor, 0, (size_t)N_NODES * 4, stream);
    prep_kernel<<<HIST_BLOCKS + 12648, 256, 0, stream>>>(x, w1l, w1r, w2l, w2r, dst,
                                                         xb, w1cat, w2cat, cursor);

    // ---- CSR build ----
    scan_local_kernel<<<NSCAN_BLOCKS, 256, 0, stream>>>(cursor, row_off, bsum);
    scan_add_kernel<<<NSCAN_BLOCKS, 256, 0, stream>>>(row_off, bsum, row_off, cursor);
    sage_fill_kernel<<<HIST_BLOCKS, 256, 0, stream>>>(src, dst, cursor, csr);

    // ---- layer 1 ----
    sage_gather_kernel<<<6256, 256, 0, stream>>>(xb, row_off, csr, aggb);
    sage_gemm1_kernel<<<784, 256, 0, stream>>>(aggb, xb, w1cat, b1l, b1r, hb);

    // ---- layer 2 (transform-then-aggregate) ----
    sage_gemm2_kernel<<<196, 256, 0, stream>>>(hb, w2cat, b2l, b2r, u, v);
    sage_gather2_kernel<<<(N_NODES + 11) / 12, 256, 0, stream>>>(u, v, row_off, csr, out);

    (void)in_sizes; (void)n_in; (void)out_size; (void)ws_size;
}